// Round 1
// baseline (2684.947 us; speedup 1.0000x reference)
//
#include <hip/hip_runtime.h>
#include <math.h>

#ifndef M_PI
#define M_PI 3.14159265358979323846
#endif

#define T_ROWS 1024
#define EDIM   2048
#define IN_DIM 1024
#define OUT_DIM 1024
#define NMODES 16
#define NBASIS 31
#define NLAYERS 4

__device__ __forceinline__ float gelu_tanh(float x) {
  // matches jax.nn.gelu(approximate=True); at these tiny magnitudes identical to exact
  float u = 0.7978845608028654f * (x + 0.044715f * x * x * x);
  return 0.5f * x * (1.0f + tanhf(u));
}

__global__ __launch_bounds__(256)
void make_tables(float* __restrict__ ctab, float* __restrict__ stab) {
  int i = blockIdx.x * 256 + threadIdx.x;
  if (i >= EDIM) return;
  double ang = (2.0 * M_PI / (double)EDIM) * (double)i;
  ctab[i] = (float)cos(ang);
  stab[i] = (float)sin(ang);
}

// basis[x][k], x in [0,1024): k<16 -> cos(2pi k x / 2048); k in [16,31) -> sin(2pi (k-15) x / 2048)
__global__ __launch_bounds__(256)
void make_basis(float* __restrict__ basis,
                const float* __restrict__ ctab, const float* __restrict__ stab) {
  int i = blockIdx.x * 256 + threadIdx.x;
  if (i >= 1024 * 32) return;
  int x = i >> 5, k = i & 31;
  float v = 0.0f;
  if (k < NMODES) v = ctab[(k * x) & (EDIM - 1)];
  else if (k < NBASIS) v = stab[((k - (NMODES - 1)) * x) & (EDIM - 1)];
  basis[i] = v;
}

// Per-layer folded weights:
//  Wmr/Wmi[l][m][d] = sum_c fc0_w[l,0,c] * (wr/wi)[l,c,d,m]
//  b0r[l][d] = N * sum_c fc0_b[l,c] * wr[l,c,d,0]      (DC bias, real part; Im(DC) dropped by irfft)
//  pw1[l][d] = sum_c fc0_w[l,0,c] * pw_w[l,c,d]
//  pb1[l][d] = sum_c fc0_b[l,c] * pw_w[l,c,d] + pw_b[l,d]
__global__ __launch_bounds__(128)
void make_layerprec(const float* __restrict__ fc0w, const float* __restrict__ fc0b,
                    const float* __restrict__ wr, const float* __restrict__ wi,
                    const float* __restrict__ pww, const float* __restrict__ pwb,
                    float* __restrict__ Wmr, float* __restrict__ Wmi,
                    float* __restrict__ b0r, float* __restrict__ pw1,
                    float* __restrict__ pb1) {
  int tid = threadIdx.x;
  if (tid >= NLAYERS * 32) return;
  int l = tid >> 5, d = tid & 31;
  for (int m = 0; m < NMODES; ++m) {
    float sr = 0.f, si = 0.f;
    for (int c = 0; c < 32; ++c) {
      float w0 = fc0w[l * 32 + c];
      size_t base = ((size_t)(l * 32 + c) * 32 + d) * NMODES + m;
      sr += w0 * wr[base];
      si += w0 * wi[base];
    }
    Wmr[(l * NMODES + m) * 32 + d] = sr;
    Wmi[(l * NMODES + m) * 32 + d] = si;
  }
  float sb = 0.f, sp = 0.f, sq = 0.f;
  for (int c = 0; c < 32; ++c) {
    float b0 = fc0b[l * 32 + c];
    float w0 = fc0w[l * 32 + c];
    sb += b0 * wr[((size_t)(l * 32 + c) * 32 + d) * NMODES + 0];
    float pw = pww[(size_t)(l * 32 + c) * 32 + d];
    sp += w0 * pw;
    sq += b0 * pw;
  }
  b0r[l * 32 + d] = (float)EDIM * sb;
  pw1[l * 32 + d] = sp;
  pb1[l * 32 + d] = sq + pwb[l * 32 + d];
}

// Fused FNO layer: one block per t, in-place on u (row staged to LDS first).
__global__ __launch_bounds__(256)
void fno_layer(float* __restrict__ u,
               const float* __restrict__ basis,
               const float* __restrict__ ctab,
               const float* __restrict__ stab,
               const float* __restrict__ Wmr,   // [16][32] (layer slice)
               const float* __restrict__ Wmi,
               const float* __restrict__ b0r,   // [32]
               const float* __restrict__ pw1,   // [32]
               const float* __restrict__ pb1,   // [32]
               const float* __restrict__ f1w,   // [32]
               const float* __restrict__ f1b)   // [1]
{
  const int t = blockIdx.x;
  const int tid = threadIdx.x;
  __shared__ float urow[EDIM];
  __shared__ float coef[NBASIS][32];
  __shared__ float red[4][32];
  __shared__ float Ush[32];
  __shared__ float l_pw1[32], l_pb1[32], l_f1[32];

  const float4* usrc = (const float4*)(u + (size_t)t * EDIM);
  for (int i = tid; i < EDIM / 4; i += 256) ((float4*)urow)[i] = usrc[i];
  if (tid < 32) { l_pw1[tid] = pw1[tid]; l_pb1[tid] = pb1[tid]; l_f1[tid] = f1w[tid]; }
  __syncthreads();

  // ---- 16-mode DFT of the row: U[m] = sum_x urow[x] * e^{-i 2pi m x / N} ----
  float pr[NMODES], pii[NMODES];
  #pragma unroll
  for (int m = 0; m < NMODES; ++m) { pr[m] = 0.f; pii[m] = 0.f; }
  #pragma unroll
  for (int it = 0; it < EDIM / 256; ++it) {
    int x = tid + it * 256;
    float val = urow[x];
    #pragma unroll
    for (int m = 0; m < NMODES; ++m) {
      int idx = (m * x) & (EDIM - 1);
      pr[m]  += val * ctab[idx];
      pii[m] -= val * stab[idx];
    }
  }
  #pragma unroll
  for (int m = 0; m < NMODES; ++m) {
    #pragma unroll
    for (int off = 32; off > 0; off >>= 1) {
      pr[m]  += __shfl_down(pr[m], off);
      pii[m] += __shfl_down(pii[m], off);
    }
  }
  int lane = tid & 63, wid = tid >> 6;
  if (lane == 0) {
    #pragma unroll
    for (int m = 0; m < NMODES; ++m) { red[wid][m] = pr[m]; red[wid][NMODES + m] = pii[m]; }
  }
  __syncthreads();
  if (tid < 32) Ush[tid] = red[0][tid] + red[1][tid] + red[2][tid] + red[3][tid];
  __syncthreads();

  // ---- Coef[k][d]: k<16 cos-coef (incl DC), k>=16 sin-coef ----
  const float invN = 1.0f / (float)EDIM;
  for (int i = tid; i < NBASIS * 32; i += 256) {
    int k = i >> 5, d = i & 31;
    int m = (k < NMODES) ? k : (k - (NMODES - 1));
    float Ur = Ush[m], Ui = Ush[NMODES + m];
    float v;
    if (k < NMODES) {
      float ofr = Ur * Wmr[m * 32 + d] - Ui * Wmi[m * 32 + d];
      v = (m == 0) ? (ofr + b0r[d]) * invN : 2.0f * ofr * invN;
    } else {
      float ofi = Ur * Wmi[m * 32 + d] + Ui * Wmr[m * 32 + d];
      v = -2.0f * ofi * invN;
    }
    coef[k][d] = v;
  }
  __syncthreads();

  const float fb = f1b[0];
  // ---- spatial reconstruction + pointwise + gelu + fc1, x and partner x+1024 ----
  for (int it = 0; it < 4; ++it) {
    int x = tid + it * 256;
    float bas[32];
    {
      const float4* bp = (const float4*)(basis + (size_t)x * 32);
      #pragma unroll
      for (int q = 0; q < 8; ++q) *(float4*)&bas[q * 4] = bp[q];
    }
    float u0 = urow[x], u1 = urow[x + 1024];
    float o0 = 0.f, o1 = 0.f;
    #pragma unroll
    for (int db = 0; db < 8; ++db) {
      float pe0=0.f,pe1=0.f,pe2=0.f,pe3=0.f, po0=0.f,po1=0.f,po2=0.f,po3=0.f;
      #pragma unroll
      for (int k = 0; k < NBASIS; ++k) {
        float4 c4 = *(const float4*)&coef[k][db * 4];
        float b = bas[k];
        int m = (k < NMODES) ? k : (k - (NMODES - 1));
        if (m & 1) { po0 += b*c4.x; po1 += b*c4.y; po2 += b*c4.z; po3 += b*c4.w; }
        else       { pe0 += b*c4.x; pe1 += b*c4.y; pe2 += b*c4.z; pe3 += b*c4.w; }
      }
      float4 w4 = *(const float4*)&l_pw1[db * 4];
      float4 q4 = *(const float4*)&l_pb1[db * 4];
      float4 f4 = *(const float4*)&l_f1[db * 4];
      float s0, s1;
      s0 = pe0+po0 + u0*w4.x + q4.x;  s1 = pe0-po0 + u1*w4.x + q4.x;
      o0 += gelu_tanh(s0)*f4.x;       o1 += gelu_tanh(s1)*f4.x;
      s0 = pe1+po1 + u0*w4.y + q4.y;  s1 = pe1-po1 + u1*w4.y + q4.y;
      o0 += gelu_tanh(s0)*f4.y;       o1 += gelu_tanh(s1)*f4.y;
      s0 = pe2+po2 + u0*w4.z + q4.z;  s1 = pe2-po2 + u1*w4.z + q4.z;
      o0 += gelu_tanh(s0)*f4.z;       o1 += gelu_tanh(s1)*f4.z;
      s0 = pe3+po3 + u0*w4.w + q4.w;  s1 = pe3-po3 + u1*w4.w + q4.w;
      o0 += gelu_tanh(s0)*f4.w;       o1 += gelu_tanh(s1)*f4.w;
    }
    u[(size_t)t * EDIM + x] = o0 + fb;
    u[(size_t)t * EDIM + x + 1024] = o1 + fb;
  }
}

// Simple fp32 tiled GEMM: C[M,N] = A[M,K] @ B[K,N] + bias[N]. BM=BN=64, BK=16, 4x4/thread.
__global__ __launch_bounds__(256)
void gemm_bias(const float* __restrict__ A, const float* __restrict__ B,
               const float* __restrict__ bias, float* __restrict__ C,
               int M, int N, int K)
{
  const int BK = 16;
  __shared__ float As[BK][64];
  __shared__ float Bs[BK][64];
  int tid = threadIdx.x;
  int tn = tid & 15, tm = tid >> 4;
  int bm = blockIdx.y * 64, bn = blockIdx.x * 64;
  float acc[4][4] = {};
  for (int k0 = 0; k0 < K; k0 += BK) {
    {
      int r = tid >> 2, c4 = (tid & 3) << 2;
      float4 a4 = *(const float4*)&A[(size_t)(bm + r) * K + k0 + c4];
      As[c4 + 0][r] = a4.x; As[c4 + 1][r] = a4.y; As[c4 + 2][r] = a4.z; As[c4 + 3][r] = a4.w;
    }
    {
      int r = tid >> 4, c4 = (tid & 15) << 2;
      *(float4*)&Bs[r][c4] = *(const float4*)&B[(size_t)(k0 + r) * N + bn + c4];
    }
    __syncthreads();
    #pragma unroll
    for (int k = 0; k < BK; ++k) {
      float4 a4 = *(const float4*)&As[k][tm * 4];
      float4 b4 = *(const float4*)&Bs[k][tn * 4];
      float a[4] = {a4.x, a4.y, a4.z, a4.w};
      float b[4] = {b4.x, b4.y, b4.z, b4.w};
      #pragma unroll
      for (int i = 0; i < 4; ++i)
        #pragma unroll
        for (int j = 0; j < 4; ++j)
          acc[i][j] += a[i] * b[j];
    }
    __syncthreads();
  }
  #pragma unroll
  for (int i = 0; i < 4; ++i) {
    int row = bm + tm * 4 + i;
    #pragma unroll
    for (int j = 0; j < 4; ++j) {
      int col = bn + tn * 4 + j;
      C[(size_t)row * N + col] = acc[i][j] + bias[col];
    }
  }
}

extern "C" void kernel_launch(void* const* d_in, const int* in_sizes, int n_in,
                              void* d_out, int out_size, void* d_ws, size_t ws_size,
                              hipStream_t stream)
{
  const float* x    = (const float*)d_in[0];
  const float* W_en = (const float*)d_in[1];
  const float* b_en = (const float*)d_in[2];
  const float* fc0w = (const float*)d_in[3];
  const float* fc0b = (const float*)d_in[4];
  const float* swr  = (const float*)d_in[5];
  const float* swi  = (const float*)d_in[6];
  const float* pww  = (const float*)d_in[7];
  const float* pwb  = (const float*)d_in[8];
  const float* f1w  = (const float*)d_in[9];
  const float* f1b  = (const float*)d_in[10];
  const float* W_de = (const float*)d_in[11];
  const float* b_de = (const float*)d_in[12];
  float* out = (float*)d_out;
  float* ws  = (float*)d_ws;

  float* u     = ws;                               // 1024*2048
  float* ctab  = u + (size_t)T_ROWS * EDIM;        // 2048
  float* stab  = ctab + EDIM;                      // 2048
  float* basis = stab + EDIM;                      // 1024*32
  float* Wmr   = basis + 1024 * 32;                // 4*16*32
  float* Wmi   = Wmr + NLAYERS * NMODES * 32;
  float* b0r   = Wmi + NLAYERS * NMODES * 32;      // 4*32
  float* pw1   = b0r + NLAYERS * 32;
  float* pb1   = pw1 + NLAYERS * 32;

  make_tables<<<EDIM / 256, 256, 0, stream>>>(ctab, stab);
  make_basis<<<(1024 * 32) / 256, 256, 0, stream>>>(basis, ctab, stab);
  make_layerprec<<<1, 128, 0, stream>>>(fc0w, fc0b, swr, swi, pww, pwb,
                                        Wmr, Wmi, b0r, pw1, pb1);

  dim3 ge(EDIM / 64, T_ROWS / 64);
  gemm_bias<<<ge, 256, 0, stream>>>(x, W_en, b_en, u, T_ROWS, EDIM, IN_DIM);

  for (int l = 0; l < NLAYERS; ++l) {
    fno_layer<<<T_ROWS, 256, 0, stream>>>(u, basis, ctab, stab,
        Wmr + l * NMODES * 32, Wmi + l * NMODES * 32,
        b0r + l * 32, pw1 + l * 32, pb1 + l * 32,
        f1w + l * 32, f1b + l);
  }

  dim3 gd(OUT_DIM / 64, T_ROWS / 64);
  gemm_bias<<<gd, 256, 0, stream>>>(u, W_de, b_de, out, T_ROWS, OUT_DIM, EDIM);
}

// Round 2
// 526.064 us; speedup vs baseline: 5.1038x; 5.1038x over previous
//
#include <hip/hip_runtime.h>
#include <math.h>

#ifndef M_PI
#define M_PI 3.14159265358979323846
#endif

#define T_ROWS 1024
#define EDIM   2048
#define IN_DIM 1024
#define OUT_DIM 1024
#define NMODES 16
#define NBASIS 31
#define NLAYERS 4

// parity-grouped basis row mapping: rows 0..14 have even m (-> pe), rows 15..30 odd m (-> po)
__device__ __forceinline__ void jmap(int j, int& isCos, int& m) {
  if (j < 15) {
    if (j < 8) { isCos = 1; m = 2 * j; }            // cos m = 0,2,...,14
    else       { isCos = 0; m = 2 * (j - 8) + 2; }  // sin m = 2,4,...,14
  } else {
    int jj = j - 15;
    if (jj < 8) { isCos = 1; m = 2 * jj + 1; }      // cos m = 1,3,...,15
    else        { isCos = 0; m = 2 * (jj - 8) + 1; }// sin m = 1,3,...,15
  }
}

__device__ __forceinline__ float gelu_fast(float x) {
  // 0.5x(1+tanh(0.79788456(x+0.044715x^3))), tanh via exp2: 1 - 2/(e^{2u}+1)
  float x2 = x * x;
  float inner = x * (0.7978845608028654f + 0.0356774081f * x2);
  float e2 = __builtin_amdgcn_exp2f(inner * 2.885390081777927f); // exp(2*inner)
  float r  = __builtin_amdgcn_rcpf(e2 + 1.0f);
  float th = 1.0f - 2.0f * r;
  return 0.5f * x * (1.0f + th);
}

__global__ __launch_bounds__(256)
void make_tables(float* __restrict__ ctab, float* __restrict__ stab) {
  int i = blockIdx.x * 256 + threadIdx.x;
  if (i >= EDIM) return;
  double ang = (2.0 * M_PI / (double)EDIM) * (double)i;
  ctab[i] = (float)cos(ang);
  stab[i] = (float)sin(ang);
}

// basT[j][x], j in [0,31), x in [0,1024) -- parity-grouped, transposed for coalesced k-outer reads
__global__ __launch_bounds__(256)
void make_basT(float* __restrict__ basT,
               const float* __restrict__ ctab, const float* __restrict__ stab) {
  int i = blockIdx.x * 256 + threadIdx.x;
  if (i >= NBASIS * 1024) return;
  int j = i >> 10, x = i & 1023;
  int isCos, m; jmap(j, isCos, m);
  int idx = (m * x) & (EDIM - 1);
  basT[i] = isCos ? ctab[idx] : stab[idx];
}

__global__ __launch_bounds__(128)
void make_layerprec(const float* __restrict__ fc0w, const float* __restrict__ fc0b,
                    const float* __restrict__ wr, const float* __restrict__ wi,
                    const float* __restrict__ pww, const float* __restrict__ pwb,
                    float* __restrict__ Wmr, float* __restrict__ Wmi,
                    float* __restrict__ b0r, float* __restrict__ pw1,
                    float* __restrict__ pb1) {
  int tid = threadIdx.x;
  if (tid >= NLAYERS * 32) return;
  int l = tid >> 5, d = tid & 31;
  for (int m = 0; m < NMODES; ++m) {
    float sr = 0.f, si = 0.f;
    for (int c = 0; c < 32; ++c) {
      float w0 = fc0w[l * 32 + c];
      size_t base = ((size_t)(l * 32 + c) * 32 + d) * NMODES + m;
      sr += w0 * wr[base];
      si += w0 * wi[base];
    }
    Wmr[(l * NMODES + m) * 32 + d] = sr;
    Wmi[(l * NMODES + m) * 32 + d] = si;
  }
  float sb = 0.f, sp = 0.f, sq = 0.f;
  for (int c = 0; c < 32; ++c) {
    float b0 = fc0b[l * 32 + c];
    float w0 = fc0w[l * 32 + c];
    sb += b0 * wr[((size_t)(l * 32 + c) * 32 + d) * NMODES + 0];
    float pw = pww[(size_t)(l * 32 + c) * 32 + d];
    sp += w0 * pw;
    sq += b0 * pw;
  }
  b0r[l * 32 + d] = (float)EDIM * sb;
  pw1[l * 32 + d] = sp;
  pb1[l * 32 + d] = sq + pwb[l * 32 + d];
}

// Kernel 1: 16-mode DFT of each row + mode mix -> coefG[t][31][32] (parity-grouped rows).
// ctab/stab staged into LDS with +i/32 skew => conflict-free gathers for all mode strides.
__global__ __launch_bounds__(256)
void dft_coef(const float* __restrict__ u,
              const float* __restrict__ ctab, const float* __restrict__ stab,
              const float* __restrict__ Wmr,   // [16][32] layer slice
              const float* __restrict__ Wmi,
              const float* __restrict__ b0r,   // [32]
              float* __restrict__ coefG)       // [T][31][32]
{
  const int t = blockIdx.x, tid = threadIdx.x;
  __shared__ float lc[EDIM + 64], ls[EDIM + 64];
  __shared__ float red[4][32];
  __shared__ float Ush[32];

  for (int i = tid; i < EDIM; i += 256) {
    int p = i + (i >> 5);
    lc[p] = ctab[i];
    ls[p] = stab[i];
  }
  float ur[8];
  #pragma unroll
  for (int it = 0; it < 8; ++it) ur[it] = u[(size_t)t * EDIM + tid + it * 256];
  __syncthreads();

  float pr[NMODES], pi[NMODES];
  #pragma unroll
  for (int m = 0; m < NMODES; ++m) { pr[m] = 0.f; pi[m] = 0.f; }
  #pragma unroll
  for (int it = 0; it < 8; ++it) {
    int x = tid + it * 256;
    float val = ur[it];
    #pragma unroll
    for (int m = 0; m < NMODES; ++m) {
      int idx = (m * x) & (EDIM - 1);
      int p = idx + (idx >> 5);
      pr[m] += val * lc[p];
      pi[m] -= val * ls[p];
    }
  }
  #pragma unroll
  for (int m = 0; m < NMODES; ++m) {
    #pragma unroll
    for (int off = 32; off > 0; off >>= 1) {
      pr[m] += __shfl_down(pr[m], off, 64);
      pi[m] += __shfl_down(pi[m], off, 64);
    }
  }
  int lane = tid & 63, wid = tid >> 6;
  if (lane == 0) {
    #pragma unroll
    for (int m = 0; m < NMODES; ++m) { red[wid][m] = pr[m]; red[wid][NMODES + m] = pi[m]; }
  }
  __syncthreads();
  if (tid < 32) Ush[tid] = red[0][tid] + red[1][tid] + red[2][tid] + red[3][tid];
  __syncthreads();

  const float invN = 1.0f / (float)EDIM;
  for (int i = tid; i < NBASIS * 32; i += 256) {
    int j = i >> 5, d = i & 31;
    int isCos, m; jmap(j, isCos, m);
    float Ur = Ush[m], Ui = Ush[NMODES + m];
    float v;
    if (isCos) {
      float ofr = Ur * Wmr[m * 32 + d] - Ui * Wmi[m * 32 + d];
      v = (m == 0) ? (ofr + b0r[d]) * invN : 2.0f * ofr * invN;
    } else {
      float ofi = Ur * Wmi[m * 32 + d] + Ui * Wmr[m * 32 + d];
      v = -2.0f * ofi * invN;
    }
    coefG[(size_t)t * (NBASIS * 32) + i] = v;
  }
}

// Kernel 2: spatial reconstruction + pointwise + gelu + fc1, in-place on u.
// No LDS. coef rows read at wave-uniform addresses (scalar-load path, K$).
// 2048 blocks: block (t, half); each thread owns x-pairs (xa, xa+1024), (xb, xb+1024).
__global__ __launch_bounds__(256, 3)
void recon(float* __restrict__ u,
           const float* __restrict__ basT,   // [31][1024]
           const float* __restrict__ coefG,  // [T][31][32]
           const float* __restrict__ pw1,    // [32]
           const float* __restrict__ pb1,    // [32]
           const float* __restrict__ f1w,    // [32]
           const float* __restrict__ f1b)    // [1]
{
  const int t = blockIdx.x >> 1, half = blockIdx.x & 1, tid = threadIdx.x;
  const int xa = half * 512 + tid;
  const int xb = xa + 256;
  const float* __restrict__ crow = coefG + (size_t)t * (NBASIS * 32);
  float* __restrict__ urow = u + (size_t)t * EDIM;

  float pe[2][32], po[2][32];
  #pragma unroll
  for (int d = 0; d < 32; ++d) { pe[0][d] = 0.f; pe[1][d] = 0.f; po[0][d] = 0.f; po[1][d] = 0.f; }

  const float u0a = urow[xa],       u1a = urow[xa + 1024];
  const float u0b = urow[xb],       u1b = urow[xb + 1024];

  // even-m rows -> pe
  for (int j = 0; j < 15; ++j) {
    float ba = basT[j * 1024 + xa];
    float bb = basT[j * 1024 + xb];
    const float* cr = crow + j * 32;
    #pragma unroll
    for (int dq = 0; dq < 8; ++dq) {
      float4 c4 = *(const float4*)(cr + dq * 4);
      pe[0][dq * 4 + 0] += ba * c4.x; pe[1][dq * 4 + 0] += bb * c4.x;
      pe[0][dq * 4 + 1] += ba * c4.y; pe[1][dq * 4 + 1] += bb * c4.y;
      pe[0][dq * 4 + 2] += ba * c4.z; pe[1][dq * 4 + 2] += bb * c4.z;
      pe[0][dq * 4 + 3] += ba * c4.w; pe[1][dq * 4 + 3] += bb * c4.w;
    }
  }
  // odd-m rows -> po
  for (int j = 15; j < 31; ++j) {
    float ba = basT[j * 1024 + xa];
    float bb = basT[j * 1024 + xb];
    const float* cr = crow + j * 32;
    #pragma unroll
    for (int dq = 0; dq < 8; ++dq) {
      float4 c4 = *(const float4*)(cr + dq * 4);
      po[0][dq * 4 + 0] += ba * c4.x; po[1][dq * 4 + 0] += bb * c4.x;
      po[0][dq * 4 + 1] += ba * c4.y; po[1][dq * 4 + 1] += bb * c4.y;
      po[0][dq * 4 + 2] += ba * c4.z; po[1][dq * 4 + 2] += bb * c4.z;
      po[0][dq * 4 + 3] += ba * c4.w; po[1][dq * 4 + 3] += bb * c4.w;
    }
  }

  const float fb = f1b[0];
  float oa0 = 0.f, oa1 = 0.f, ob0 = 0.f, ob1 = 0.f;
  #pragma unroll
  for (int d = 0; d < 32; ++d) {
    float w = pw1[d], q = pb1[d], f = f1w[d];
    float s;
    s = pe[0][d] + po[0][d] + u0a * w + q;  oa0 += gelu_fast(s) * f;
    s = pe[0][d] - po[0][d] + u1a * w + q;  oa1 += gelu_fast(s) * f;
    s = pe[1][d] + po[1][d] + u0b * w + q;  ob0 += gelu_fast(s) * f;
    s = pe[1][d] - po[1][d] + u1b * w + q;  ob1 += gelu_fast(s) * f;
  }
  urow[xa]        = oa0 + fb;
  urow[xa + 1024] = oa1 + fb;
  urow[xb]        = ob0 + fb;
  urow[xb + 1024] = ob1 + fb;
}

// fp32 tiled GEMM: C[M,N] = A[M,K] @ B[K,N] + bias[N]. BM=BN=64, BK=16, 4x4/thread.
__global__ __launch_bounds__(256)
void gemm_bias(const float* __restrict__ A, const float* __restrict__ B,
               const float* __restrict__ bias, float* __restrict__ C,
               int M, int N, int K)
{
  const int BK = 16;
  __shared__ float As[BK][64];
  __shared__ float Bs[BK][64];
  int tid = threadIdx.x;
  int tn = tid & 15, tm = tid >> 4;
  int bm = blockIdx.y * 64, bn = blockIdx.x * 64;
  float acc[4][4] = {};
  for (int k0 = 0; k0 < K; k0 += BK) {
    {
      int r = tid >> 2, c4 = (tid & 3) << 2;
      float4 a4 = *(const float4*)&A[(size_t)(bm + r) * K + k0 + c4];
      As[c4 + 0][r] = a4.x; As[c4 + 1][r] = a4.y; As[c4 + 2][r] = a4.z; As[c4 + 3][r] = a4.w;
    }
    {
      int r = tid >> 4, c4 = (tid & 15) << 2;
      *(float4*)&Bs[r][c4] = *(const float4*)&B[(size_t)(k0 + r) * N + bn + c4];
    }
    __syncthreads();
    #pragma unroll
    for (int k = 0; k < BK; ++k) {
      float4 a4 = *(const float4*)&As[k][tm * 4];
      float4 b4 = *(const float4*)&Bs[k][tn * 4];
      float a[4] = {a4.x, a4.y, a4.z, a4.w};
      float b[4] = {b4.x, b4.y, b4.z, b4.w};
      #pragma unroll
      for (int i = 0; i < 4; ++i)
        #pragma unroll
        for (int j = 0; j < 4; ++j)
          acc[i][j] += a[i] * b[j];
    }
    __syncthreads();
  }
  #pragma unroll
  for (int i = 0; i < 4; ++i) {
    int row = bm + tm * 4 + i;
    #pragma unroll
    for (int j = 0; j < 4; ++j) {
      int col = bn + tn * 4 + j;
      C[(size_t)row * N + col] = acc[i][j] + bias[col];
    }
  }
}

extern "C" void kernel_launch(void* const* d_in, const int* in_sizes, int n_in,
                              void* d_out, int out_size, void* d_ws, size_t ws_size,
                              hipStream_t stream)
{
  const float* x    = (const float*)d_in[0];
  const float* W_en = (const float*)d_in[1];
  const float* b_en = (const float*)d_in[2];
  const float* fc0w = (const float*)d_in[3];
  const float* fc0b = (const float*)d_in[4];
  const float* swr  = (const float*)d_in[5];
  const float* swi  = (const float*)d_in[6];
  const float* pww  = (const float*)d_in[7];
  const float* pwb  = (const float*)d_in[8];
  const float* f1w  = (const float*)d_in[9];
  const float* f1b  = (const float*)d_in[10];
  const float* W_de = (const float*)d_in[11];
  const float* b_de = (const float*)d_in[12];
  float* out = (float*)d_out;
  float* ws  = (float*)d_ws;

  float* u     = ws;                                  // 1024*2048
  float* ctab  = u + (size_t)T_ROWS * EDIM;           // 2048
  float* stab  = ctab + EDIM;                         // 2048
  float* basT  = stab + EDIM;                         // 31*1024
  float* Wmr   = basT + NBASIS * 1024;                // 4*16*32
  float* Wmi   = Wmr + NLAYERS * NMODES * 32;         // 4*16*32
  float* b0r   = Wmi + NLAYERS * NMODES * 32;         // 4*32
  float* pw1   = b0r + NLAYERS * 32;                  // 4*32
  float* pb1   = pw1 + NLAYERS * 32;                  // 4*32
  float* coefG = pb1 + NLAYERS * 32;                  // 1024*31*32 (~4MB)

  make_tables<<<EDIM / 256, 256, 0, stream>>>(ctab, stab);
  make_basT<<<(NBASIS * 1024 + 255) / 256, 256, 0, stream>>>(basT, ctab, stab);
  make_layerprec<<<1, 128, 0, stream>>>(fc0w, fc0b, swr, swi, pww, pwb,
                                        Wmr, Wmi, b0r, pw1, pb1);

  dim3 ge(EDIM / 64, T_ROWS / 64);
  gemm_bias<<<ge, 256, 0, stream>>>(x, W_en, b_en, u, T_ROWS, EDIM, IN_DIM);

  for (int l = 0; l < NLAYERS; ++l) {
    dft_coef<<<T_ROWS, 256, 0, stream>>>(u, ctab, stab,
        Wmr + l * NMODES * 32, Wmi + l * NMODES * 32, b0r + l * 32, coefG);
    recon<<<2 * T_ROWS, 256, 0, stream>>>(u, basT, coefG,
        pw1 + l * 32, pb1 + l * 32, f1w + l * 32, f1b + l);
  }

  dim3 gd(OUT_DIM / 64, T_ROWS / 64);
  gemm_bias<<<gd, 256, 0, stream>>>(u, W_de, b_de, out, T_ROWS, OUT_DIM, EDIM);
}

// Round 3
// 411.350 us; speedup vs baseline: 6.5272x; 1.2789x over previous
//
#include <hip/hip_runtime.h>
#include <math.h>

#ifndef M_PI
#define M_PI 3.14159265358979323846
#endif

#define T_ROWS 1024
#define EDIM   2048
#define IN_DIM 1024
#define OUT_DIM 1024
#define NMODES 16
#define NBASIS 31
#define NLAYERS 4

typedef __attribute__((ext_vector_type(8))) short bf16x8;
typedef __attribute__((ext_vector_type(4))) float f32x4;

__device__ __forceinline__ unsigned short f2bf(float f) {
  union { float f; unsigned u; } v; v.f = f;
  unsigned r = v.u + 0x7FFFu + ((v.u >> 16) & 1u);  // RNE
  return (unsigned short)(r >> 16);
}

// parity-grouped basis row mapping: rows 0..14 even m (-> pe), rows 15..30 odd m (-> po)
__device__ __forceinline__ void jmap(int j, int& isCos, int& m) {
  if (j < 15) {
    if (j < 8) { isCos = 1; m = 2 * j; }
    else       { isCos = 0; m = 2 * (j - 8) + 2; }
  } else {
    int jj = j - 15;
    if (jj < 8) { isCos = 1; m = 2 * jj + 1; }
    else        { isCos = 0; m = 2 * (jj - 8) + 1; }
  }
}

__device__ __forceinline__ float gelu_fast(float x) {
  float x2 = x * x;
  float inner = x * (0.7978845608028654f + 0.0356774081f * x2);
  float e2 = __builtin_amdgcn_exp2f(inner * 2.885390081777927f);
  float r  = __builtin_amdgcn_rcpf(e2 + 1.0f);
  return 0.5f * x * (2.0f - 2.0f * r);
}

// Fused setup: blocks 0..7 tables, 8..131 basT (direct fp64 trig), 132 layerprec.
__global__ __launch_bounds__(256)
void setup_all(float* __restrict__ ctab, float* __restrict__ stab,
               float* __restrict__ basT,
               const float* __restrict__ fc0w, const float* __restrict__ fc0b,
               const float* __restrict__ wr, const float* __restrict__ wi,
               const float* __restrict__ pww, const float* __restrict__ pwb,
               float* __restrict__ Wmr, float* __restrict__ Wmi,
               float* __restrict__ b0r, float* __restrict__ pw1,
               float* __restrict__ pb1)
{
  const int b = blockIdx.x, tid = threadIdx.x;
  if (b < 8) {
    int i = b * 256 + tid;
    double ang = (2.0 * M_PI / (double)EDIM) * (double)i;
    ctab[i] = (float)cos(ang);
    stab[i] = (float)sin(ang);
  } else if (b < 132) {
    int i = (b - 8) * 256 + tid;          // < 31744 = 31*1024 exactly
    int j = i >> 10, x = i & 1023;
    int isCos, m; jmap(j, isCos, m);
    int idx = (m * x) & (EDIM - 1);
    double ang = (2.0 * M_PI / (double)EDIM) * (double)idx;
    basT[i] = isCos ? (float)cos(ang) : (float)sin(ang);
  } else {
    if (tid >= NLAYERS * 32) return;
    int l = tid >> 5, d = tid & 31;
    for (int m = 0; m < NMODES; ++m) {
      float sr = 0.f, si = 0.f;
      for (int c = 0; c < 32; ++c) {
        float w0 = fc0w[l * 32 + c];
        size_t base = ((size_t)(l * 32 + c) * 32 + d) * NMODES + m;
        sr += w0 * wr[base];
        si += w0 * wi[base];
      }
      Wmr[(l * NMODES + m) * 32 + d] = sr;
      Wmi[(l * NMODES + m) * 32 + d] = si;
    }
    float sb = 0.f, sp = 0.f, sq = 0.f;
    for (int c = 0; c < 32; ++c) {
      float b0 = fc0b[l * 32 + c];
      float w0 = fc0w[l * 32 + c];
      sb += b0 * wr[((size_t)(l * 32 + c) * 32 + d) * NMODES + 0];
      float pw = pww[(size_t)(l * 32 + c) * 32 + d];
      sp += w0 * pw;
      sq += b0 * pw;
    }
    b0r[l * 32 + d] = (float)EDIM * sb;
    pw1[l * 32 + d] = sp;
    pb1[l * 32 + d] = sq + pwb[l * 32 + d];
  }
}

// B[K][N] fp32 -> BT[N][K] bf16, 32x32 tiles
__global__ __launch_bounds__(256)
void transpose_cvt(const float* __restrict__ B, unsigned short* __restrict__ BT,
                   int K, int N)
{
  __shared__ float tile[32][33];
  const int k0 = blockIdx.y * 32, n0 = blockIdx.x * 32;
  const int tid = threadIdx.x;
  {
    int r = tid >> 3, c4 = (tid & 7) * 4;
    float4 v = *(const float4*)&B[(size_t)(k0 + r) * N + n0 + c4];
    tile[r][c4 + 0] = v.x; tile[r][c4 + 1] = v.y;
    tile[r][c4 + 2] = v.z; tile[r][c4 + 3] = v.w;
  }
  __syncthreads();
  {
    int n = tid >> 3, kq = (tid & 7) * 4;
    ushort4 o;
    o.x = f2bf(tile[kq + 0][n]); o.y = f2bf(tile[kq + 1][n]);
    o.z = f2bf(tile[kq + 2][n]); o.w = f2bf(tile[kq + 3][n]);
    *(ushort4*)&BT[(size_t)(n0 + n) * K + k0 + kq] = o;
  }
}

// C[M][N] = A[M][K](fp32, cvt->bf16 on stage) @ BT[N][K](bf16)^T + bias
// 64x64 tile, BK=32, 4 waves -> 32x32 quadrant each (2x2 of 16x16x32 MFMA).
#define BKK 32
__global__ __launch_bounds__(256)
void gemm_mfma(const float* __restrict__ A, const unsigned short* __restrict__ BT,
               const float* __restrict__ bias, float* __restrict__ C,
               int M, int N, int K)
{
  __shared__ __align__(16) unsigned short Asb[64 * BKK];
  __shared__ __align__(16) unsigned short Bsb[64 * BKK];
  const int tid = threadIdx.x;
  const int bm = blockIdx.y * 64, bn = blockIdx.x * 64;
  const int lane = tid & 63, wave = tid >> 6;
  const int wr = wave >> 1, wc = wave & 1;

  const int srow  = tid >> 2;                    // 0..63
  const int skb   = tid & 3;                     // 0..3
  const int sslot = skb ^ ((srow >> 1) & 3);

  const int frow = lane & 15;
  const int fkb  = lane >> 4;                    // 0..3

  f32x4 acc[2][2] = {};

  const float* aRow = A + (size_t)(bm + srow) * K + skb * 8;
  const unsigned short* bRow = BT + (size_t)(bn + srow) * K + skb * 8;
  unsigned short* aDst = &Asb[srow * BKK + sslot * 8];
  unsigned short* bDst = &Bsb[srow * BKK + sslot * 8];

  for (int k0 = 0; k0 < K; k0 += BKK) {
    {
      float4 a0 = *(const float4*)(aRow + k0);
      float4 a1 = *(const float4*)(aRow + k0 + 4);
      union { unsigned short u[8]; bf16x8 v; } pk;
      pk.u[0] = f2bf(a0.x); pk.u[1] = f2bf(a0.y); pk.u[2] = f2bf(a0.z); pk.u[3] = f2bf(a0.w);
      pk.u[4] = f2bf(a1.x); pk.u[5] = f2bf(a1.y); pk.u[6] = f2bf(a1.z); pk.u[7] = f2bf(a1.w);
      *(bf16x8*)aDst = pk.v;
    }
    {
      *(bf16x8*)bDst = *(const bf16x8*)(bRow + k0);
    }
    __syncthreads();
    bf16x8 a[2], b[2];
    #pragma unroll
    for (int i = 0; i < 2; ++i) {
      int ar = wr * 32 + i * 16 + frow;
      a[i] = *(const bf16x8*)&Asb[ar * BKK + (fkb ^ ((ar >> 1) & 3)) * 8];
      int br = wc * 32 + i * 16 + frow;
      b[i] = *(const bf16x8*)&Bsb[br * BKK + (fkb ^ ((br >> 1) & 3)) * 8];
    }
    #pragma unroll
    for (int i = 0; i < 2; ++i)
      #pragma unroll
      for (int j = 0; j < 2; ++j)
        acc[i][j] = __builtin_amdgcn_mfma_f32_16x16x32_bf16(a[i], b[j], acc[i][j], 0, 0, 0);
    __syncthreads();
  }

  #pragma unroll
  for (int j = 0; j < 2; ++j) {
    int col = bn + wc * 32 + j * 16 + (lane & 15);
    float bz = bias[col];
    #pragma unroll
    for (int i = 0; i < 2; ++i) {
      #pragma unroll
      for (int r = 0; r < 4; ++r) {
        int row = bm + wr * 32 + i * 16 + (lane >> 4) * 4 + r;
        C[(size_t)row * N + col] = acc[i][j][r] + bz;
      }
    }
  }
}

// Kernel 1: 16-mode DFT of each row + mode mix -> coefG[t][31][32]
__global__ __launch_bounds__(256)
void dft_coef(const float* __restrict__ u,
              const float* __restrict__ ctab, const float* __restrict__ stab,
              const float* __restrict__ Wmr, const float* __restrict__ Wmi,
              const float* __restrict__ b0r, float* __restrict__ coefG)
{
  const int t = blockIdx.x, tid = threadIdx.x;
  __shared__ float lc[EDIM + 64], ls[EDIM + 64];
  __shared__ float red[4][32];
  __shared__ float Ush[32];

  for (int i = tid; i < EDIM; i += 256) {
    int p = i + (i >> 5);
    lc[p] = ctab[i];
    ls[p] = stab[i];
  }
  float ur[8];
  #pragma unroll
  for (int it = 0; it < 8; ++it) ur[it] = u[(size_t)t * EDIM + tid + it * 256];
  __syncthreads();

  float pr[NMODES], pi[NMODES];
  #pragma unroll
  for (int m = 0; m < NMODES; ++m) { pr[m] = 0.f; pi[m] = 0.f; }
  #pragma unroll
  for (int it = 0; it < 8; ++it) {
    int x = tid + it * 256;
    float val = ur[it];
    #pragma unroll
    for (int m = 0; m < NMODES; ++m) {
      int idx = (m * x) & (EDIM - 1);
      int p = idx + (idx >> 5);
      pr[m] += val * lc[p];
      pi[m] -= val * ls[p];
    }
  }
  #pragma unroll
  for (int m = 0; m < NMODES; ++m) {
    #pragma unroll
    for (int off = 32; off > 0; off >>= 1) {
      pr[m] += __shfl_down(pr[m], off, 64);
      pi[m] += __shfl_down(pi[m], off, 64);
    }
  }
  int lane = tid & 63, wid = tid >> 6;
  if (lane == 0) {
    #pragma unroll
    for (int m = 0; m < NMODES; ++m) { red[wid][m] = pr[m]; red[wid][NMODES + m] = pi[m]; }
  }
  __syncthreads();
  if (tid < 32) Ush[tid] = red[0][tid] + red[1][tid] + red[2][tid] + red[3][tid];
  __syncthreads();

  const float invN = 1.0f / (float)EDIM;
  for (int i = tid; i < NBASIS * 32; i += 256) {
    int j = i >> 5, d = i & 31;
    int isCos, m; jmap(j, isCos, m);
    float Ur = Ush[m], Ui = Ush[NMODES + m];
    float v;
    if (isCos) {
      float ofr = Ur * Wmr[m * 32 + d] - Ui * Wmi[m * 32 + d];
      v = (m == 0) ? (ofr + b0r[d]) * invN : 2.0f * ofr * invN;
    } else {
      float ofi = Ur * Wmi[m * 32 + d] + Ui * Wmr[m * 32 + d];
      v = -2.0f * ofi * invN;
    }
    coefG[(size_t)t * (NBASIS * 32) + i] = v;
  }
}

// Kernel 2: reconstruction + pointwise + gelu + fc1, in-place on u.
__global__ __launch_bounds__(256, 3)
void recon(float* __restrict__ u,
           const float* __restrict__ basT, const float* __restrict__ coefG,
           const float* __restrict__ pw1, const float* __restrict__ pb1,
           const float* __restrict__ f1w, const float* __restrict__ f1b)
{
  const int t = blockIdx.x >> 1, half = blockIdx.x & 1, tid = threadIdx.x;
  const int xa = half * 512 + tid;
  const int xb = xa + 256;
  const float* __restrict__ crow = coefG + (size_t)t * (NBASIS * 32);
  float* __restrict__ urow = u + (size_t)t * EDIM;

  float pe[2][32], po[2][32];
  #pragma unroll
  for (int d = 0; d < 32; ++d) { pe[0][d] = 0.f; pe[1][d] = 0.f; po[0][d] = 0.f; po[1][d] = 0.f; }

  const float u0a = urow[xa], u1a = urow[xa + 1024];
  const float u0b = urow[xb], u1b = urow[xb + 1024];

  for (int j = 0; j < 15; ++j) {
    float ba = basT[j * 1024 + xa];
    float bb = basT[j * 1024 + xb];
    const float* cr = crow + j * 32;
    #pragma unroll
    for (int dq = 0; dq < 8; ++dq) {
      float4 c4 = *(const float4*)(cr + dq * 4);
      pe[0][dq * 4 + 0] += ba * c4.x; pe[1][dq * 4 + 0] += bb * c4.x;
      pe[0][dq * 4 + 1] += ba * c4.y; pe[1][dq * 4 + 1] += bb * c4.y;
      pe[0][dq * 4 + 2] += ba * c4.z; pe[1][dq * 4 + 2] += bb * c4.z;
      pe[0][dq * 4 + 3] += ba * c4.w; pe[1][dq * 4 + 3] += bb * c4.w;
    }
  }
  for (int j = 15; j < 31; ++j) {
    float ba = basT[j * 1024 + xa];
    float bb = basT[j * 1024 + xb];
    const float* cr = crow + j * 32;
    #pragma unroll
    for (int dq = 0; dq < 8; ++dq) {
      float4 c4 = *(const float4*)(cr + dq * 4);
      po[0][dq * 4 + 0] += ba * c4.x; po[1][dq * 4 + 0] += bb * c4.x;
      po[0][dq * 4 + 1] += ba * c4.y; po[1][dq * 4 + 1] += bb * c4.y;
      po[0][dq * 4 + 2] += ba * c4.z; po[1][dq * 4 + 2] += bb * c4.z;
      po[0][dq * 4 + 3] += ba * c4.w; po[1][dq * 4 + 3] += bb * c4.w;
    }
  }

  const float fb = f1b[0];
  float oa0 = 0.f, oa1 = 0.f, ob0 = 0.f, ob1 = 0.f;
  #pragma unroll
  for (int d = 0; d < 32; ++d) {
    float w = pw1[d], q = pb1[d], f = f1w[d];
    float s;
    s = pe[0][d] + po[0][d] + u0a * w + q;  oa0 += gelu_fast(s) * f;
    s = pe[0][d] - po[0][d] + u1a * w + q;  oa1 += gelu_fast(s) * f;
    s = pe[1][d] + po[1][d] + u0b * w + q;  ob0 += gelu_fast(s) * f;
    s = pe[1][d] - po[1][d] + u1b * w + q;  ob1 += gelu_fast(s) * f;
  }
  urow[xa]        = oa0 + fb;
  urow[xa + 1024] = oa1 + fb;
  urow[xb]        = ob0 + fb;
  urow[xb + 1024] = ob1 + fb;
}

extern "C" void kernel_launch(void* const* d_in, const int* in_sizes, int n_in,
                              void* d_out, int out_size, void* d_ws, size_t ws_size,
                              hipStream_t stream)
{
  const float* x    = (const float*)d_in[0];
  const float* W_en = (const float*)d_in[1];
  const float* b_en = (const float*)d_in[2];
  const float* fc0w = (const float*)d_in[3];
  const float* fc0b = (const float*)d_in[4];
  const float* swr  = (const float*)d_in[5];
  const float* swi  = (const float*)d_in[6];
  const float* pww  = (const float*)d_in[7];
  const float* pwb  = (const float*)d_in[8];
  const float* f1w  = (const float*)d_in[9];
  const float* f1b  = (const float*)d_in[10];
  const float* W_de = (const float*)d_in[11];
  const float* b_de = (const float*)d_in[12];
  float* out = (float*)d_out;
  float* ws  = (float*)d_ws;

  float* u     = ws;                                  // 1024*2048
  float* ctab  = u + (size_t)T_ROWS * EDIM;           // 2048
  float* stab  = ctab + EDIM;                         // 2048
  float* basT  = stab + EDIM;                         // 31*1024
  float* Wmr   = basT + NBASIS * 1024;                // 4*16*32
  float* Wmi   = Wmr + NLAYERS * NMODES * 32;         // 4*16*32
  float* b0r   = Wmi + NLAYERS * NMODES * 32;         // 4*32
  float* pw1   = b0r + NLAYERS * 32;                  // 4*32
  float* pb1   = pw1 + NLAYERS * 32;                  // 4*32
  float* coefG = pb1 + NLAYERS * 32;                  // 1024*31*32
  unsigned short* WenT = (unsigned short*)(coefG + (size_t)T_ROWS * NBASIS * 32); // [2048][1024] bf16
  unsigned short* WdeT = WenT + (size_t)EDIM * IN_DIM;                            // [1024][2048] bf16

  setup_all<<<133, 256, 0, stream>>>(ctab, stab, basT, fc0w, fc0b, swr, swi,
                                     pww, pwb, Wmr, Wmi, b0r, pw1, pb1);

  { dim3 g(EDIM / 32, IN_DIM / 32);
    transpose_cvt<<<g, 256, 0, stream>>>(W_en, WenT, IN_DIM, EDIM); }
  { dim3 g(OUT_DIM / 32, EDIM / 32);
    transpose_cvt<<<g, 256, 0, stream>>>(W_de, WdeT, EDIM, OUT_DIM); }

  { dim3 g(EDIM / 64, T_ROWS / 64);
    gemm_mfma<<<g, 256, 0, stream>>>(x, WenT, b_en, u, T_ROWS, EDIM, IN_DIM); }

  for (int l = 0; l < NLAYERS; ++l) {
    dft_coef<<<T_ROWS, 256, 0, stream>>>(u, ctab, stab,
        Wmr + l * NMODES * 32, Wmi + l * NMODES * 32, b0r + l * 32, coefG);
    recon<<<2 * T_ROWS, 256, 0, stream>>>(u, basT, coefG,
        pw1 + l * 32, pb1 + l * 32, f1w + l * 32, f1b + l);
  }

  { dim3 g(OUT_DIM / 64, T_ROWS / 64);
    gemm_mfma<<<g, 256, 0, stream>>>(u, WdeT, b_de, out, T_ROWS, OUT_DIM, EDIM); }
}

// Round 4
// 337.185 us; speedup vs baseline: 7.9628x; 1.2200x over previous
//
#include <hip/hip_runtime.h>
#include <math.h>

#ifndef M_PI
#define M_PI 3.14159265358979323846
#endif

#define T_ROWS 1024
#define EDIM   2048
#define IN_DIM 1024
#define OUT_DIM 1024
#define NMODES 16
#define NLAYERS 4

typedef __attribute__((ext_vector_type(8))) short bf16x8;
typedef __attribute__((ext_vector_type(4))) float f32x4;

__device__ __forceinline__ unsigned short f2bf(float f) {
  union { float f; unsigned u; } v; v.f = f;
  unsigned r = v.u + 0x7FFFu + ((v.u >> 16) & 1u);  // RNE
  return (unsigned short)(r >> 16);
}
__device__ __forceinline__ float bf2f(unsigned short h) {
  union { unsigned u; float f; } v; v.u = ((unsigned)h) << 16;
  return v.f;
}
__device__ __forceinline__ void f2bf_split(float v, unsigned short& h, unsigned short& l) {
  h = f2bf(v);
  l = f2bf(v - bf2f(h));
}

__device__ __forceinline__ float gelu_fast(float x) {
  float x2 = x * x;
  float inner = x * (0.7978845608028654f + 0.0356774081f * x2);
  float e2 = __builtin_amdgcn_exp2f(inner * 2.885390081777927f);
  float r  = __builtin_amdgcn_rcpf(e2 + 1.0f);
  return 0.5f * x * (2.0f - 2.0f * r);
}

// Fused setup.
// blocks 0..7: ctab/stab (for dft_coef LDS staging)
// blocks 8..263: basF hi/lo fragment table: [128 mt][64 lane][8 i]
//   x = mt*16 + (lane&15), j = (lane>>4)*8 + i; j<16: cos(2pi j x/2048),
//   16<=j<31: sin(2pi (j-15) x/2048), j==31: 0   (A-frag order for 16x16x32)
// block 264: folded layer weights
__global__ __launch_bounds__(256)
void setup_all(float* __restrict__ ctab, float* __restrict__ stab,
               unsigned short* __restrict__ basFh, unsigned short* __restrict__ basFl,
               const float* __restrict__ fc0w, const float* __restrict__ fc0b,
               const float* __restrict__ wr, const float* __restrict__ wi,
               const float* __restrict__ pww, const float* __restrict__ pwb,
               float* __restrict__ Wmr, float* __restrict__ Wmi,
               float* __restrict__ b0r, float* __restrict__ pw1,
               float* __restrict__ pb1)
{
  const int b = blockIdx.x, tid = threadIdx.x;
  if (b < 8) {
    int i = b * 256 + tid;
    double ang = (2.0 * M_PI / (double)EDIM) * (double)i;
    ctab[i] = (float)cos(ang);
    stab[i] = (float)sin(ang);
  } else if (b < 264) {
    int idx = (b - 8) * 256 + tid;            // [0, 65536)
    int mt = idx >> 9;
    int l  = (idx >> 3) & 63;
    int i  = idx & 7;
    int x  = mt * 16 + (l & 15);
    int j  = (l >> 4) * 8 + i;
    float v = 0.0f;
    if (j < 31) {
      int m = (j < NMODES) ? j : (j - 15);
      int ia = (m * x) & (EDIM - 1);
      double ang = (2.0 * M_PI / (double)EDIM) * (double)ia;
      v = (j < NMODES) ? (float)cos(ang) : (float)sin(ang);
    }
    unsigned short h, lo; f2bf_split(v, h, lo);
    basFh[idx] = h; basFl[idx] = lo;
  } else {
    if (tid >= NLAYERS * 32) return;
    int l = tid >> 5, d = tid & 31;
    for (int m = 0; m < NMODES; ++m) {
      float sr = 0.f, si = 0.f;
      for (int c = 0; c < 32; ++c) {
        float w0 = fc0w[l * 32 + c];
        size_t base = ((size_t)(l * 32 + c) * 32 + d) * NMODES + m;
        sr += w0 * wr[base];
        si += w0 * wi[base];
      }
      Wmr[(l * NMODES + m) * 32 + d] = sr;
      Wmi[(l * NMODES + m) * 32 + d] = si;
    }
    float sb = 0.f, sp = 0.f, sq = 0.f;
    for (int c = 0; c < 32; ++c) {
      float b0 = fc0b[l * 32 + c];
      float w0 = fc0w[l * 32 + c];
      sb += b0 * wr[((size_t)(l * 32 + c) * 32 + d) * NMODES + 0];
      float pw = pww[(size_t)(l * 32 + c) * 32 + d];
      sp += w0 * pw;
      sq += b0 * pw;
    }
    b0r[l * 32 + d] = (float)EDIM * sb;
    pw1[l * 32 + d] = sp;
    pb1[l * 32 + d] = sq + pwb[l * 32 + d];
  }
}

// B[K][N] fp32 -> BT[N][K] bf16, 32x32 tiles
__global__ __launch_bounds__(256)
void transpose_cvt(const float* __restrict__ B, unsigned short* __restrict__ BT,
                   int K, int N)
{
  __shared__ float tile[32][33];
  const int k0 = blockIdx.y * 32, n0 = blockIdx.x * 32;
  const int tid = threadIdx.x;
  {
    int r = tid >> 3, c4 = (tid & 7) * 4;
    float4 v = *(const float4*)&B[(size_t)(k0 + r) * N + n0 + c4];
    tile[r][c4 + 0] = v.x; tile[r][c4 + 1] = v.y;
    tile[r][c4 + 2] = v.z; tile[r][c4 + 3] = v.w;
  }
  __syncthreads();
  {
    int n = tid >> 3, kq = (tid & 7) * 4;
    ushort4 o;
    o.x = f2bf(tile[kq + 0][n]); o.y = f2bf(tile[kq + 1][n]);
    o.z = f2bf(tile[kq + 2][n]); o.w = f2bf(tile[kq + 3][n]);
    *(ushort4*)&BT[(size_t)(n0 + n) * K + k0 + kq] = o;
  }
}

// C[M][N] = A[M][K](fp32 -> bf16 on stage) @ BT[N][K]^T + bias. 64x64 tile, BK=64.
#define BKK 64
__global__ __launch_bounds__(256)
void gemm_mfma(const float* __restrict__ A, const unsigned short* __restrict__ BT,
               const float* __restrict__ bias, float* __restrict__ C,
               int M, int N, int K)
{
  __shared__ __align__(16) unsigned short Asb[64 * BKK];
  __shared__ __align__(16) unsigned short Bsb[64 * BKK];
  const int tid = threadIdx.x;
  const int bm = blockIdx.y * 64, bn = blockIdx.x * 64;
  const int lane = tid & 63, wave = tid >> 6;
  const int wr = wave >> 1, wc = wave & 1;

  const int srow = tid >> 2;          // 0..63
  const int skq  = tid & 3;           // 16-k chunk

  f32x4 acc[2][2] = {};

  const float* aRow = A + (size_t)(bm + srow) * K + skq * 16;
  const unsigned short* bRow = BT + (size_t)(bn + srow) * K + skq * 16;

  for (int k0 = 0; k0 < K; k0 += BKK) {
    #pragma unroll
    for (int h = 0; h < 2; ++h) {
      int kb = skq * 2 + h;
      int slot = kb ^ ((srow >> 1) & 7);
      {
        float4 a0 = *(const float4*)(aRow + k0 + h * 8);
        float4 a1 = *(const float4*)(aRow + k0 + h * 8 + 4);
        union { unsigned short u[8]; bf16x8 v; } pk;
        pk.u[0] = f2bf(a0.x); pk.u[1] = f2bf(a0.y); pk.u[2] = f2bf(a0.z); pk.u[3] = f2bf(a0.w);
        pk.u[4] = f2bf(a1.x); pk.u[5] = f2bf(a1.y); pk.u[6] = f2bf(a1.z); pk.u[7] = f2bf(a1.w);
        *(bf16x8*)&Asb[srow * BKK + slot * 8] = pk.v;
      }
      *(bf16x8*)&Bsb[srow * BKK + slot * 8] = *(const bf16x8*)(bRow + k0 + h * 8);
    }
    __syncthreads();
    #pragma unroll
    for (int s = 0; s < 2; ++s) {
      int kb = s * 4 + (lane >> 4);
      bf16x8 a[2], b[2];
      #pragma unroll
      for (int i = 0; i < 2; ++i) {
        int ar = wr * 32 + i * 16 + (lane & 15);
        a[i] = *(const bf16x8*)&Asb[ar * BKK + (kb ^ ((ar >> 1) & 7)) * 8];
        int br = wc * 32 + i * 16 + (lane & 15);
        b[i] = *(const bf16x8*)&Bsb[br * BKK + (kb ^ ((br >> 1) & 7)) * 8];
      }
      #pragma unroll
      for (int i = 0; i < 2; ++i)
        #pragma unroll
        for (int j = 0; j < 2; ++j)
          acc[i][j] = __builtin_amdgcn_mfma_f32_16x16x32_bf16(a[i], b[j], acc[i][j], 0, 0, 0);
    }
    __syncthreads();
  }

  #pragma unroll
  for (int j = 0; j < 2; ++j) {
    int col = bn + wc * 32 + j * 16 + (lane & 15);
    float bz = bias[col];
    #pragma unroll
    for (int i = 0; i < 2; ++i)
      #pragma unroll
      for (int r = 0; r < 4; ++r) {
        int row = bm + wr * 32 + i * 16 + (lane >> 4) * 4 + r;
        C[(size_t)row * N + col] = acc[i][j][r] + bz;
      }
  }
}

// 16-mode DFT per row + mode mix -> bf16 hi/lo B-fragments coefF[t][n][lane][8]
__global__ __launch_bounds__(256)
void dft_coef(const float* __restrict__ u,
              const float* __restrict__ ctab, const float* __restrict__ stab,
              const float* __restrict__ Wmr, const float* __restrict__ Wmi,
              const float* __restrict__ b0r,
              unsigned short* __restrict__ coefFh, unsigned short* __restrict__ coefFl)
{
  const int t = blockIdx.x, tid = threadIdx.x;
  __shared__ float lc[EDIM + 64], ls[EDIM + 64];
  __shared__ float red[4][32];
  __shared__ float Ush[32];

  for (int i = tid; i < EDIM; i += 256) {
    int p = i + (i >> 5);
    lc[p] = ctab[i];
    ls[p] = stab[i];
  }
  float ur[8];
  #pragma unroll
  for (int it = 0; it < 8; ++it) ur[it] = u[(size_t)t * EDIM + tid + it * 256];
  __syncthreads();

  float pr[NMODES], pi[NMODES];
  #pragma unroll
  for (int m = 0; m < NMODES; ++m) { pr[m] = 0.f; pi[m] = 0.f; }
  #pragma unroll
  for (int it = 0; it < 8; ++it) {
    int x = tid + it * 256;
    float val = ur[it];
    #pragma unroll
    for (int m = 0; m < NMODES; ++m) {
      int idx = (m * x) & (EDIM - 1);
      int p = idx + (idx >> 5);
      pr[m] += val * lc[p];
      pi[m] -= val * ls[p];
    }
  }
  #pragma unroll
  for (int m = 0; m < NMODES; ++m) {
    #pragma unroll
    for (int off = 32; off > 0; off >>= 1) {
      pr[m] += __shfl_down(pr[m], off, 64);
      pi[m] += __shfl_down(pi[m], off, 64);
    }
  }
  int lane = tid & 63, wid = tid >> 6;
  if (lane == 0) {
    #pragma unroll
    for (int m = 0; m < NMODES; ++m) { red[wid][m] = pr[m]; red[wid][NMODES + m] = pi[m]; }
  }
  __syncthreads();
  if (tid < 32) Ush[tid] = red[0][tid] + red[1][tid] + red[2][tid] + red[3][tid];
  __syncthreads();

  if (tid < 128) {
    const float invN = 1.0f / (float)EDIM;
    int n = tid >> 6, l = tid & 63;
    int d = n * 16 + (l & 15);
    union { unsigned short u[8]; bf16x8 v; } ph, pl;
    #pragma unroll
    for (int i = 0; i < 8; ++i) {
      int j = (l >> 4) * 8 + i;
      float v = 0.f;
      if (j < 31) {
        if (j < NMODES) {
          int m = j;
          float ofr = Ush[m] * Wmr[m * 32 + d] - Ush[NMODES + m] * Wmi[m * 32 + d];
          v = (m == 0) ? (ofr + b0r[d]) * invN : 2.0f * ofr * invN;
        } else {
          int m = j - 15;
          float ofi = Ush[m] * Wmi[m * 32 + d] + Ush[NMODES + m] * Wmr[m * 32 + d];
          v = -2.0f * ofi * invN;
        }
      }
      f2bf_split(v, ph.u[i], pl.u[i]);
    }
    size_t base = ((size_t)t * 2 + n) * 64 + l;
    *(bf16x8*)&coefFh[base * 8] = ph.v;
    *(bf16x8*)&coefFl[base * 8] = pl.v;
  }
}

// MFMA reconstruction + gelu + fc1, in-place on u. One block = 2 t-rows.
// v1 = bas @ coef via split bf16 (bh@ch + bh@cl + bl@ch), C-frags bounced
// through wave-private LDS to give each lane one whole x for the epilogue.
__global__ __launch_bounds__(256)
void recon_mfma(float* __restrict__ u,
                const unsigned short* __restrict__ basFh,
                const unsigned short* __restrict__ basFl,
                const unsigned short* __restrict__ coefFh,
                const unsigned short* __restrict__ coefFl,
                const float* __restrict__ pw1, const float* __restrict__ pb1,
                const float* __restrict__ f1w, const float* __restrict__ f1b)
{
  const int t0 = blockIdx.x * 2;
  const int tid = threadIdx.x, lane = tid & 63, w = tid >> 6;
  __shared__ float vbuf[4][64][36];

  bf16x8 ch[2][2], cl[2][2];
  #pragma unroll
  for (int tt = 0; tt < 2; ++tt)
    #pragma unroll
    for (int n = 0; n < 2; ++n) {
      size_t base = (((size_t)(t0 + tt) * 2 + n) * 64 + lane) * 8;
      ch[tt][n] = *(const bf16x8*)&coefFh[base];
      cl[tt][n] = *(const bf16x8*)&coefFl[base];
    }
  const float fb = f1b[0];
  const int g = lane >> 4, m15 = lane & 15;

  for (int c = 0; c < 8; ++c) {
    const int mtb = w * 32 + c * 4;
    f32x4 acc[4][2][2];
    #pragma unroll
    for (int q = 0; q < 4; ++q) {
      const int mt = mtb + q;
      bf16x8 bh = *(const bf16x8*)&basFh[((size_t)mt * 64 + lane) * 8];
      bf16x8 bl = *(const bf16x8*)&basFl[((size_t)mt * 64 + lane) * 8];
      #pragma unroll
      for (int tt = 0; tt < 2; ++tt)
        #pragma unroll
        for (int n = 0; n < 2; ++n) {
          f32x4 a = {};
          a = __builtin_amdgcn_mfma_f32_16x16x32_bf16(bl, ch[tt][n], a, 0, 0, 0);
          a = __builtin_amdgcn_mfma_f32_16x16x32_bf16(bh, cl[tt][n], a, 0, 0, 0);
          a = __builtin_amdgcn_mfma_f32_16x16x32_bf16(bh, ch[tt][n], a, 0, 0, 0);
          acc[q][tt][n] = a;
        }
    }
    #pragma unroll
    for (int tt = 0; tt < 2; ++tt) {
      #pragma unroll
      for (int q = 0; q < 4; ++q)
        #pragma unroll
        for (int n = 0; n < 2; ++n)
          #pragma unroll
          for (int r = 0; r < 4; ++r)
            vbuf[w][q * 16 + g * 4 + r][n * 16 + m15] = acc[q][tt][n][r];
      // wave-private buffer: in-wave ds ordering via compiler waitcnts, no barrier
      const int x = w * 512 + c * 64 + lane;
      float* __restrict__ up = u + (size_t)(t0 + tt) * EDIM + x;
      const float uval = *up;
      float o = 0.f;
      #pragma unroll
      for (int dc = 0; dc < 8; ++dc) {
        f32x4 v4 = *(const f32x4*)&vbuf[w][lane][dc * 4];
        float4 pwv = *(const float4*)&pw1[dc * 4];
        float4 pbv = *(const float4*)&pb1[dc * 4];
        float4 fv  = *(const float4*)&f1w[dc * 4];
        float s;
        s = v4[0] + uval * pwv.x + pbv.x;  o += gelu_fast(s) * fv.x;
        s = v4[1] + uval * pwv.y + pbv.y;  o += gelu_fast(s) * fv.y;
        s = v4[2] + uval * pwv.z + pbv.z;  o += gelu_fast(s) * fv.z;
        s = v4[3] + uval * pwv.w + pbv.w;  o += gelu_fast(s) * fv.w;
      }
      *up = o + fb;
    }
  }
}

extern "C" void kernel_launch(void* const* d_in, const int* in_sizes, int n_in,
                              void* d_out, int out_size, void* d_ws, size_t ws_size,
                              hipStream_t stream)
{
  const float* x    = (const float*)d_in[0];
  const float* W_en = (const float*)d_in[1];
  const float* b_en = (const float*)d_in[2];
  const float* fc0w = (const float*)d_in[3];
  const float* fc0b = (const float*)d_in[4];
  const float* swr  = (const float*)d_in[5];
  const float* swi  = (const float*)d_in[6];
  const float* pww  = (const float*)d_in[7];
  const float* pwb  = (const float*)d_in[8];
  const float* f1w  = (const float*)d_in[9];
  const float* f1b  = (const float*)d_in[10];
  const float* W_de = (const float*)d_in[11];
  const float* b_de = (const float*)d_in[12];
  float* out = (float*)d_out;
  float* ws  = (float*)d_ws;

  float* u    = ws;                                   // 1024*2048
  float* ctab = u + (size_t)T_ROWS * EDIM;            // 2048
  float* stab = ctab + EDIM;                          // 2048
  float* Wmr  = stab + EDIM;                          // 4*16*32
  float* Wmi  = Wmr + NLAYERS * NMODES * 32;          // 4*16*32
  float* b0r  = Wmi + NLAYERS * NMODES * 32;          // 4*32
  float* pw1  = b0r + NLAYERS * 32;                   // 4*32
  float* pb1  = pw1 + NLAYERS * 32;                   // 4*32
  unsigned short* basFh  = (unsigned short*)(pb1 + NLAYERS * 32);   // 128*64*8
  unsigned short* basFl  = basFh + 128 * 64 * 8;                    // 128*64*8
  unsigned short* coefFh = basFl + 128 * 64 * 8;                    // 1024*2*64*8
  unsigned short* coefFl = coefFh + (size_t)T_ROWS * 2 * 64 * 8;
  unsigned short* WenT   = coefFl + (size_t)T_ROWS * 2 * 64 * 8;    // [2048][1024]
  unsigned short* WdeT   = WenT + (size_t)EDIM * IN_DIM;            // [1024][2048]

  setup_all<<<265, 256, 0, stream>>>(ctab, stab, basFh, basFl, fc0w, fc0b,
                                     swr, swi, pww, pwb, Wmr, Wmi, b0r, pw1, pb1);

  { dim3 g(EDIM / 32, IN_DIM / 32);
    transpose_cvt<<<g, 256, 0, stream>>>(W_en, WenT, IN_DIM, EDIM); }
  { dim3 g(OUT_DIM / 32, EDIM / 32);
    transpose_cvt<<<g, 256, 0, stream>>>(W_de, WdeT, EDIM, OUT_DIM); }

  { dim3 g(EDIM / 64, T_ROWS / 64);
    gemm_mfma<<<g, 256, 0, stream>>>(x, WenT, b_en, u, T_ROWS, EDIM, IN_DIM); }

  for (int l = 0; l < NLAYERS; ++l) {
    dft_coef<<<T_ROWS, 256, 0, stream>>>(u, ctab, stab,
        Wmr + l * NMODES * 32, Wmi + l * NMODES * 32, b0r + l * 32,
        coefFh, coefFl);
    recon_mfma<<<T_ROWS / 2, 256, 0, stream>>>(u, basFh, basFl, coefFh, coefFl,
        pw1 + l * 32, pb1 + l * 32, f1w + l * 32, f1b + l);
  }

  { dim3 g(OUT_DIM / 64, T_ROWS / 64);
    gemm_mfma<<<g, 256, 0, stream>>>(u, WdeT, b_de, out, T_ROWS, OUT_DIM, EDIM); }
}